// Round 3
// baseline (320.474 us; speedup 1.0000x reference)
//
#include <hip/hip_runtime.h>
#include <hip/hip_bf16.h>
#include <stdint.h>

// Problem dims (fixed by reference)
#define NB 16384
#define ND 1024
#define NH 2048
#define NE 8
#define NC 3
#define MAXWL 136  // max active (e,mt) tiles: ceil(16384/128)+7

typedef __attribute__((ext_vector_type(8))) short short8;
typedef __attribute__((ext_vector_type(4))) short short4v;
typedef __attribute__((ext_vector_type(4))) float f32x4;

// fp32 -> bf16 round-to-nearest-even
__device__ __forceinline__ unsigned short f2bf(float f) {
  union { float f; unsigned int u; } v; v.f = f;
  unsigned int u = v.u;
  return (unsigned short)((u + 0x7fffu + ((u >> 16) & 1u)) >> 16);
}

// async global->LDS, 16B per lane (LDS dest linear in lane order)
__device__ __forceinline__ void glds16(const void* g, void* l) {
  __builtin_amdgcn_global_load_lds(
      (const __attribute__((address_space(1))) void*)g,
      (__attribute__((address_space(3))) void*)l,
      16, 0, 0);
}

// ---------------------------------------------------------------------------
// Kernel 1: fused prep. Parity-interleaved so the two independent memory
// streams (router reading x, transpose reading W1) overlap on-device.
//   even blocks: router — one wave per row, fp32 logits (argmax must match
//                numpy fp32), writes topics[row] only.
//   odd blocks : W1 [E][D][H] f32 -> W1T [E][H][D] bf16, LDS-tiled.
// ---------------------------------------------------------------------------
__global__ __launch_bounds__(256) void prep_kernel(
    const float* __restrict__ x, const float* __restrict__ Wr,
    const float* __restrict__ br, const float* __restrict__ W1,
    int* __restrict__ topics, unsigned short* __restrict__ w1t) {
  __shared__ float tile[64][65];
  int bid = blockIdx.x;
  int t = threadIdx.x;
  if ((bid & 1) == 0) {
    // ---- router ----
    int w = t >> 6, lane = t & 63;
    int row = (bid >> 1) * 4 + w;
    const float* xr = x + (size_t)row * ND;
    float p[NE] = {0.f, 0.f, 0.f, 0.f, 0.f, 0.f, 0.f, 0.f};
#pragma unroll
    for (int i = 0; i < 4; ++i) {
      int k0 = i * 256 + lane * 4;
      f32x4 xv = *(const f32x4*)(xr + k0);
#pragma unroll
      for (int j = 0; j < 4; ++j) {
        const f32x4* wp = (const f32x4*)(Wr + (size_t)(k0 + j) * NE);
        f32x4 wa = wp[0], wb = wp[1];  // 32KB Wr lives in cache
        float xj = xv[j];
        p[0] = fmaf(xj, wa[0], p[0]);
        p[1] = fmaf(xj, wa[1], p[1]);
        p[2] = fmaf(xj, wa[2], p[2]);
        p[3] = fmaf(xj, wa[3], p[3]);
        p[4] = fmaf(xj, wb[0], p[4]);
        p[5] = fmaf(xj, wb[1], p[5]);
        p[6] = fmaf(xj, wb[2], p[6]);
        p[7] = fmaf(xj, wb[3], p[7]);
      }
    }
#pragma unroll
    for (int e = 0; e < NE; ++e) {
#pragma unroll
      for (int d = 1; d < 64; d <<= 1) p[e] += __shfl_xor(p[e], d);
    }
    if (lane == 0) {
      float best = -1e30f;
      int bi = 0;
#pragma unroll
      for (int e = 0; e < NE; ++e) {
        float v = p[e] + br[e];
        if (v > best) { best = v; bi = e; }  // strict > : first max (numpy)
      }
      topics[row] = bi;
    }
  } else {
    // ---- W1 transpose+convert ----
    int wid = bid >> 1;
    int e = wid >> 9;
    int rem = wid & 511;
    int kb = rem >> 5;
    int hb = rem & 31;
    const float* src = W1 + ((size_t)e * ND + kb * 64) * NH + hb * 64;
#pragma unroll
    for (int i = 0; i < 4; ++i) {
      int idx = i * 256 + t;
      int kl = idx >> 4;
      int h0 = (idx & 15) * 4;
      f32x4 v = *(const f32x4*)(src + (size_t)kl * NH + h0);
      tile[kl][h0 + 0] = v[0];
      tile[kl][h0 + 1] = v[1];
      tile[kl][h0 + 2] = v[2];
      tile[kl][h0 + 3] = v[3];
    }
    __syncthreads();
    unsigned short* dst = w1t + ((size_t)e * NH + hb * 64) * ND + kb * 64;
#pragma unroll
    for (int i = 0; i < 4; ++i) {
      int idx = i * 256 + t;
      int hl = idx >> 4;
      int kq = (idx & 15) * 4;
      short4v s;
#pragma unroll
      for (int j = 0; j < 4; ++j) s[j] = (short)f2bf(tile[kq + j][hl]);
      *(short4v*)(dst + (size_t)hl * ND + kq) = s;  // 8B/lane coalesced
    }
  }
}

// ---------------------------------------------------------------------------
// Kernel 2: ranker. ONE block, 1024 threads, 16 rows/thread.
// Packed-u16 Hillis-Steele scan of per-thread 8-expert histograms ->
// stable rank -> perm scatter + counts/offsets + worklist.
// ---------------------------------------------------------------------------
__global__ __launch_bounds__(1024) void ranker_kernel(
    const int* __restrict__ topics, int* __restrict__ perm,
    int* __restrict__ counts, int* __restrict__ offsets,
    int* __restrict__ worklist, int* __restrict__ n_wl) {
  int tid = threadIdx.x;
  __shared__ uint4 sbuf[1024];
  __shared__ int soff[NE];

  int t[16];
  const int4* tp = (const int4*)(topics + tid * 16);
#pragma unroll
  for (int i = 0; i < 4; ++i) {
    int4 v = tp[i];
    t[i * 4 + 0] = v.x; t[i * 4 + 1] = v.y;
    t[i * 4 + 2] = v.z; t[i * 4 + 3] = v.w;
  }
  int h[NE] = {0, 0, 0, 0, 0, 0, 0, 0};
#pragma unroll
  for (int i = 0; i < 16; ++i) {
#pragma unroll
    for (int q = 0; q < NE; ++q) h[q] += (t[i] == q);
  }
  uint4 pk;
  pk.x = (unsigned)h[0] | ((unsigned)h[1] << 16);
  pk.y = (unsigned)h[2] | ((unsigned)h[3] << 16);
  pk.z = (unsigned)h[4] | ((unsigned)h[5] << 16);
  pk.w = (unsigned)h[6] | ((unsigned)h[7] << 16);
  uint4 own = pk;
  sbuf[tid] = pk;
  __syncthreads();
  for (int d = 1; d < 1024; d <<= 1) {
    uint4 v = {0u, 0u, 0u, 0u};
    if (tid >= d) v = sbuf[tid - d];
    __syncthreads();
    pk.x += v.x; pk.y += v.y; pk.z += v.z; pk.w += v.w;
    sbuf[tid] = pk;
    __syncthreads();
  }
  if (tid == 0) {
    uint4 tot = sbuf[1023];
    int c[NE] = {(int)(tot.x & 0xffff), (int)(tot.x >> 16),
                 (int)(tot.y & 0xffff), (int)(tot.y >> 16),
                 (int)(tot.z & 0xffff), (int)(tot.z >> 16),
                 (int)(tot.w & 0xffff), (int)(tot.w >> 16)};
    int s = 0, nw = 0;
    for (int e = 0; e < NE; ++e) {
      counts[e] = c[e];
      offsets[e] = s;
      soff[e] = s;
      s += c[e];
      for (int mt = 0; mt * 128 < c[e]; ++mt) worklist[nw++] = (e << 16) | mt;
    }
    *n_wl = nw;
  }
  __syncthreads();
  uint4 ex;
  ex.x = pk.x - own.x; ex.y = pk.y - own.y;
  ex.z = pk.z - own.z; ex.w = pk.w - own.w;
  int r[NE] = {soff[0] + (int)(ex.x & 0xffff), soff[1] + (int)(ex.x >> 16),
               soff[2] + (int)(ex.y & 0xffff), soff[3] + (int)(ex.y >> 16),
               soff[4] + (int)(ex.z & 0xffff), soff[5] + (int)(ex.z >> 16),
               soff[6] + (int)(ex.w & 0xffff), soff[7] + (int)(ex.w >> 16)};
#pragma unroll
  for (int i = 0; i < 16; ++i) {
    int e = t[i];
    int pos = 0;
#pragma unroll
    for (int q = 0; q < NE; ++q) pos = (e == q) ? r[q] : pos;
    perm[pos] = tid * 16 + i;
#pragma unroll
    for (int q = 0; q < NE; ++q) r[q] += (e == q);
  }
}

// ---------------------------------------------------------------------------
// Kernel 3: gather. xg[pos] = bf16(x[perm[pos]]) — makes the gemm's
// A-operand physically contiguous (round-2 lesson: the in-gemm row gather
// was ~128 random 128B L3 transactions per K-iter = the latency wall).
// Streaming: 64MB read (L3-hot) + 32MB write. Also inits out = b2[topic].
// One wave per gathered row.
// ---------------------------------------------------------------------------
__global__ __launch_bounds__(256) void gather_kernel(
    const float* __restrict__ x, const int* __restrict__ perm,
    const int* __restrict__ topics, const float* __restrict__ b2,
    unsigned short* __restrict__ xg, float* __restrict__ out) {
  int w = threadIdx.x >> 6, lane = threadIdx.x & 63;
  int pos = blockIdx.x * 4 + w;
  int tok = perm[pos];
  const float* src = x + (size_t)tok * ND;
  unsigned short* dst = xg + (size_t)pos * ND;
#pragma unroll
  for (int i = 0; i < 4; ++i) {
    int k0 = i * 256 + lane * 4;
    f32x4 v = *(const f32x4*)(src + k0);
    short4v s;
#pragma unroll
    for (int j = 0; j < 4; ++j) s[j] = (short)f2bf(v[j]);
    *(short4v*)(dst + k0) = s;
  }
  if (lane == 0) {
    int e = topics[tok];
    out[tok * NC + 0] = b2[e * NC + 0];
    out[tok * NC + 1] = b2[e * NC + 1];
    out[tok * NC + 2] = b2[e * NC + 2];
  }
}

// ---------------------------------------------------------------------------
// Kernel 4: fused gathered GEMM + bias/relu + W2 reduce + atomic combine.
// 128x128 tile, BK=64, 4 waves x (4x4) 16x16x32 bf16 MFMA frags.
// A rows now CONTIGUOUS (xg): both staging streams fully coalesced.
// LDS chunk XOR-swizzle (pre-swizzled global source + swizzled ds_read).
// perm needed only for the epilogue scatter.
// ---------------------------------------------------------------------------
__global__ __launch_bounds__(256) void moe_gemm_kernel(
    const unsigned short* __restrict__ xg, const unsigned short* __restrict__ w1t,
    const float* __restrict__ b1, const float* __restrict__ W2,
    const int* __restrict__ perm, const int* __restrict__ counts,
    const int* __restrict__ offsets, const int* __restrict__ worklist,
    const int* __restrict__ n_wl, float* __restrict__ out) {
  int nt = blockIdx.x & 15;   // B panel; XCD = bid%8 = nt%8 -> B L2-local
  int wi = blockIdx.x >> 4;
  if (wi >= *n_wl) return;
  int item = worklist[wi];
  int e = item >> 16;
  int mt = item & 0xffff;
  int cnt = counts[e];
  int off = offsets[e];
  int off128 = off + mt * 128;
  int t = threadIdx.x;
  int lane = t & 63;
  int w = t >> 6, wr = w >> 1, wc = w & 1;

  __shared__ int ridx[128];
  __shared__ unsigned short As[128 * 64];  // slot(r,c) holds chunk c^(r&7)
  __shared__ unsigned short Bs[128 * 64];

  if (t < 128) {
    int m = mt * 128 + t;
    ridx[t] = perm[off + (m < cnt ? m : cnt - 1)];  // epilogue only
  }

  // staging addresses: 16B chunk c of row r sourced from global chunk c^(r&7)
  const unsigned short* aptr[4];
  const unsigned short* bptr[4];
  char* dstA[4];
  char* dstB[4];
#pragma unroll
  for (int i = 0; i < 4; ++i) {
    int idx = i * 256 + t;
    int r = idx >> 3;
    int c = idx & 7;
    int cs = c ^ (r & 7);
    aptr[i] = xg + (size_t)(off128 + r) * ND + cs * 8;  // contiguous rows
    bptr[i] = w1t + ((size_t)(e * NH + nt * 128 + r)) * ND + cs * 8;
    dstA[i] = (char*)As + idx * 16;
    dstB[i] = (char*)Bs + idx * 16;
  }

  // hoist epilogue weights above K-loop
  int cg = lane & 15;
  int g = lane >> 4;
  float b1v[4];
  float w2v[4][3];
#pragma unroll
  for (int n = 0; n < 4; ++n) {
    int col = nt * 128 + wc * 64 + n * 16 + cg;
    b1v[n] = b1[e * NH + col];
    const float* w2p = W2 + ((size_t)e * NH + col) * NC;
    w2v[n][0] = w2p[0];
    w2v[n][1] = w2p[1];
    w2v[n][2] = w2p[2];
  }

  f32x4 acc[4][4];
#pragma unroll
  for (int m = 0; m < 4; ++m)
#pragma unroll
    for (int n = 0; n < 4; ++n) acc[m][n] = (f32x4){0.f, 0.f, 0.f, 0.f};

  int arow = (wr * 64 + (lane & 15)) * 64;
  int brow = (wc * 64 + (lane & 15)) * 64;
  int sx = lane & 7;

  for (int kt = 0; kt < ND; kt += 64) {
#pragma unroll
    for (int i = 0; i < 4; ++i) {
      glds16(aptr[i] + kt, dstA[i]);
      glds16(bptr[i] + kt, dstB[i]);
    }
    __syncthreads();
#pragma unroll
    for (int kk = 0; kk < 2; ++kk) {
      int ch = ((kk * 4 + g) ^ sx) * 8;
      short8 af[4], bfr[4];
#pragma unroll
      for (int m = 0; m < 4; ++m)
        af[m] = *(const short8*)&As[arow + m * 1024 + ch];
#pragma unroll
      for (int n = 0; n < 4; ++n)
        bfr[n] = *(const short8*)&Bs[brow + n * 1024 + ch];
#pragma unroll
      for (int m = 0; m < 4; ++m)
#pragma unroll
        for (int n = 0; n < 4; ++n)
          acc[m][n] = __builtin_amdgcn_mfma_f32_16x16x32_bf16(
              af[m], bfr[n], acc[m][n], 0, 0, 0);
    }
    __syncthreads();
  }

  // Epilogue: h = relu(acc + b1); out[row][c] += sum_h h * W2[h][c]
  // C/D frag mapping: col = lane&15, row = (lane>>4)*4 + i   [m89/m91]
#pragma unroll
  for (int m = 0; m < 4; ++m) {
#pragma unroll
    for (int i = 0; i < 4; ++i) {
      float s0 = 0.f, s1 = 0.f, s2 = 0.f;
#pragma unroll
      for (int n = 0; n < 4; ++n) {
        float h = acc[m][n][i] + b1v[n];
        h = h > 0.f ? h : 0.f;
        s0 = fmaf(h, w2v[n][0], s0);
        s1 = fmaf(h, w2v[n][1], s1);
        s2 = fmaf(h, w2v[n][2], s2);
      }
#pragma unroll
      for (int d = 1; d < 16; d <<= 1) {
        s0 += __shfl_xor(s0, d);
        s1 += __shfl_xor(s1, d);
        s2 += __shfl_xor(s2, d);
      }
      if (cg == 0) {
        int rloc = wr * 64 + m * 16 + g * 4 + i;
        if (mt * 128 + rloc < cnt) {
          int tok = ridx[rloc];
          atomicAdd(&out[tok * NC + 0], s0);
          atomicAdd(&out[tok * NC + 1], s1);
          atomicAdd(&out[tok * NC + 2], s2);
        }
      }
    }
  }
}

// ---------------------------------------------------------------------------
// Workspace layout (~64.2 MB):
//   [0,   32MiB)   xg  (gathered bf16 x, expert-sorted) [16384][1024]
//   [32,  64MiB)   W1T bf16 [8][2048][1024]
//   [64MiB ...)    topics[16384], perm[16384], counts[8], offsets[8],
//                  worklist[256], n_wl
// (gemm A-tail overshoot of <=127 rows reads into the W1T region — valid
//  memory, small bf16 values, results discarded by the cnt guard.)
// ---------------------------------------------------------------------------
extern "C" void kernel_launch(void* const* d_in, const int* in_sizes, int n_in,
                              void* d_out, int out_size, void* d_ws,
                              size_t ws_size, hipStream_t stream) {
  const float* x = (const float*)d_in[0];
  const float* Wr = (const float*)d_in[1];
  const float* br = (const float*)d_in[2];
  const float* W1 = (const float*)d_in[3];
  const float* b1 = (const float*)d_in[4];
  const float* W2 = (const float*)d_in[5];
  const float* b2 = (const float*)d_in[6];
  float* out = (float*)d_out;

  char* ws = (char*)d_ws;
  unsigned short* xg = (unsigned short*)ws;
  unsigned short* w1t = (unsigned short*)(ws + (size_t)33554432);
  int* topics = (int*)(ws + (size_t)67108864);
  int* perm = topics + NB;
  int* counts = perm + NB;
  int* offsets = counts + NE;
  int* worklist = offsets + NE;
  int* n_wl = worklist + 256;

  prep_kernel<<<8192, 256, 0, stream>>>(x, Wr, br, W1, topics, w1t);
  ranker_kernel<<<1, 1024, 0, stream>>>(topics, perm, counts, offsets,
                                        worklist, n_wl);
  gather_kernel<<<NB / 4, 256, 0, stream>>>(x, perm, topics, b2, xg, out);
  moe_gemm_kernel<<<MAXWL * 16, 256, 0, stream>>>(xg, w1t, b1, W2, perm,
                                                  counts, offsets, worklist,
                                                  n_wl, out);
}

// Round 5
// 200.534 us; speedup vs baseline: 1.5981x; 1.5981x over previous
//
#include <hip/hip_runtime.h>
#include <hip/hip_bf16.h>
#include <stdint.h>

// Problem dims (fixed by reference)
#define NB 16384
#define ND 1024
#define NH 2048
#define NE 8
#define NC 3
#define MAXWL 136  // max active (e,mt) tiles: ceil(16384/128)+7

typedef __attribute__((ext_vector_type(8))) short short8;
typedef __attribute__((ext_vector_type(4))) short short4v;
typedef __attribute__((ext_vector_type(4))) float f32x4;

// fp32 -> bf16 round-to-nearest-even
__device__ __forceinline__ unsigned short f2bf(float f) {
  union { float f; unsigned int u; } v; v.f = f;
  unsigned int u = v.u;
  return (unsigned short)((u + 0x7fffu + ((u >> 16) & 1u)) >> 16);
}

// async global->LDS, 16B per lane (LDS dest linear in lane order)
__device__ __forceinline__ void glds16(const void* g, void* l) {
  __builtin_amdgcn_global_load_lds(
      (const __attribute__((address_space(1))) void*)g,
      (__attribute__((address_space(3))) void*)l,
      16, 0, 0);
}

// ---------------------------------------------------------------------------
// Kernel 1: router. One wave per row. Fused x->bf16 conversion. fp32 logits
// (argmax must match numpy fp32). Writes topics only — NO atomics.
// ---------------------------------------------------------------------------
__global__ __launch_bounds__(256) void router_kernel(
    const float* __restrict__ x, const float* __restrict__ Wr,
    const float* __restrict__ br, unsigned short* __restrict__ xb,
    int* __restrict__ topics) {
  int w = threadIdx.x >> 6, lane = threadIdx.x & 63;
  int row = blockIdx.x * 4 + w;
  const float* xr = x + (size_t)row * ND;
  unsigned short* xbr = xb + (size_t)row * ND;
  float p[NE] = {0.f, 0.f, 0.f, 0.f, 0.f, 0.f, 0.f, 0.f};
#pragma unroll
  for (int i = 0; i < 4; ++i) {
    int k0 = i * 256 + lane * 4;
    f32x4 xv = *(const f32x4*)(xr + k0);
    short4v s;
#pragma unroll
    for (int j = 0; j < 4; ++j) s[j] = (short)f2bf(xv[j]);
    *(short4v*)(xbr + k0) = s;  // coalesced 8B/lane
#pragma unroll
    for (int j = 0; j < 4; ++j) {
      const f32x4* wp = (const f32x4*)(Wr + (size_t)(k0 + j) * NE);
      f32x4 wa = wp[0], wb = wp[1];  // 32KB Wr lives in cache
      float xj = xv[j];
      p[0] = fmaf(xj, wa[0], p[0]);
      p[1] = fmaf(xj, wa[1], p[1]);
      p[2] = fmaf(xj, wa[2], p[2]);
      p[3] = fmaf(xj, wa[3], p[3]);
      p[4] = fmaf(xj, wb[0], p[4]);
      p[5] = fmaf(xj, wb[1], p[5]);
      p[6] = fmaf(xj, wb[2], p[6]);
      p[7] = fmaf(xj, wb[3], p[7]);
    }
  }
#pragma unroll
  for (int e = 0; e < NE; ++e) {
#pragma unroll
    for (int d = 1; d < 64; d <<= 1) p[e] += __shfl_xor(p[e], d);
  }
  if (lane == 0) {
    float best = -1e30f;
    int bi = 0;
#pragma unroll
    for (int e = 0; e < NE; ++e) {
      float v = p[e] + br[e];
      if (v > best) { best = v; bi = e; }  // strict > : first max (numpy)
    }
    topics[row] = bi;
  }
}

// ---------------------------------------------------------------------------
// Kernel 2: ranker. ONE block, 1024 threads, 16 rows/thread.
// Packed-u16 Hillis-Steele scan of per-thread 8-expert histograms ->
// stable rank -> perm scatter + counts/offsets + worklist.
// ---------------------------------------------------------------------------
__global__ __launch_bounds__(1024) void ranker_kernel(
    const int* __restrict__ topics, int* __restrict__ perm,
    int* __restrict__ counts, int* __restrict__ offsets,
    int* __restrict__ worklist, int* __restrict__ n_wl) {
  int tid = threadIdx.x;
  __shared__ uint4 sbuf[1024];
  __shared__ int soff[NE];

  int t[16];
  const int4* tp = (const int4*)(topics + tid * 16);
#pragma unroll
  for (int i = 0; i < 4; ++i) {
    int4 v = tp[i];
    t[i * 4 + 0] = v.x; t[i * 4 + 1] = v.y;
    t[i * 4 + 2] = v.z; t[i * 4 + 3] = v.w;
  }
  int h[NE] = {0, 0, 0, 0, 0, 0, 0, 0};
#pragma unroll
  for (int i = 0; i < 16; ++i) {
#pragma unroll
    for (int q = 0; q < NE; ++q) h[q] += (t[i] == q);
  }
  uint4 pk;
  pk.x = (unsigned)h[0] | ((unsigned)h[1] << 16);
  pk.y = (unsigned)h[2] | ((unsigned)h[3] << 16);
  pk.z = (unsigned)h[4] | ((unsigned)h[5] << 16);
  pk.w = (unsigned)h[6] | ((unsigned)h[7] << 16);
  uint4 own = pk;
  sbuf[tid] = pk;
  __syncthreads();
  for (int d = 1; d < 1024; d <<= 1) {
    uint4 v = {0u, 0u, 0u, 0u};
    if (tid >= d) v = sbuf[tid - d];
    __syncthreads();
    pk.x += v.x; pk.y += v.y; pk.z += v.z; pk.w += v.w;
    sbuf[tid] = pk;
    __syncthreads();
  }
  if (tid == 0) {
    uint4 tot = sbuf[1023];
    int c[NE] = {(int)(tot.x & 0xffff), (int)(tot.x >> 16),
                 (int)(tot.y & 0xffff), (int)(tot.y >> 16),
                 (int)(tot.z & 0xffff), (int)(tot.z >> 16),
                 (int)(tot.w & 0xffff), (int)(tot.w >> 16)};
    int s = 0, nw = 0;
    for (int e = 0; e < NE; ++e) {
      counts[e] = c[e];
      offsets[e] = s;
      soff[e] = s;
      s += c[e];
      for (int mt = 0; mt * 128 < c[e]; ++mt) worklist[nw++] = (e << 16) | mt;
    }
    *n_wl = nw;
  }
  __syncthreads();
  uint4 ex;
  ex.x = pk.x - own.x; ex.y = pk.y - own.y;
  ex.z = pk.z - own.z; ex.w = pk.w - own.w;
  int r[NE] = {soff[0] + (int)(ex.x & 0xffff), soff[1] + (int)(ex.x >> 16),
               soff[2] + (int)(ex.y & 0xffff), soff[3] + (int)(ex.y >> 16),
               soff[4] + (int)(ex.z & 0xffff), soff[5] + (int)(ex.z >> 16),
               soff[6] + (int)(ex.w & 0xffff), soff[7] + (int)(ex.w >> 16)};
#pragma unroll
  for (int i = 0; i < 16; ++i) {
    int e = t[i];
    int pos = 0;
#pragma unroll
    for (int q = 0; q < NE; ++q) pos = (e == q) ? r[q] : pos;
    perm[pos] = tid * 16 + i;
#pragma unroll
    for (int q = 0; q < NE; ++q) r[q] += (e == q);
  }
}

// ---------------------------------------------------------------------------
// Kernel 3: W1 [E][D][H] f32 -> W1T [E][H][D] bf16, LDS-tiled, vectorized.
// ---------------------------------------------------------------------------
__global__ __launch_bounds__(256) void w1t_kernel(
    const float* __restrict__ W1, unsigned short* __restrict__ w1t) {
  __shared__ float tile[64][65];
  int bid = blockIdx.x;
  int e = bid >> 9;
  int rem = bid & 511;
  int kb = rem >> 5;
  int hb = rem & 31;
  int t = threadIdx.x;
  const float* src = W1 + ((size_t)e * ND + kb * 64) * NH + hb * 64;
#pragma unroll
  for (int i = 0; i < 4; ++i) {
    int idx = i * 256 + t;
    int kl = idx >> 4;
    int h0 = (idx & 15) * 4;
    f32x4 v = *(const f32x4*)(src + (size_t)kl * NH + h0);
    tile[kl][h0 + 0] = v[0];
    tile[kl][h0 + 1] = v[1];
    tile[kl][h0 + 2] = v[2];
    tile[kl][h0 + 3] = v[3];
  }
  __syncthreads();
  unsigned short* dst = w1t + ((size_t)e * NH + hb * 64) * ND + kb * 64;
#pragma unroll
  for (int i = 0; i < 4; ++i) {
    int idx = i * 256 + t;
    int hl = idx >> 4;
    int kq = (idx & 15) * 4;
    short4v s;
#pragma unroll
    for (int j = 0; j < 4; ++j) s[j] = (short)f2bf(tile[kq + j][hl]);
    *(short4v*)(dst + (size_t)hl * ND + kq) = s;  // 8B/lane coalesced
  }
}

// ---------------------------------------------------------------------------
// Kernel 4: fused gathered GEMM + bias/relu + W2 reduce -> PARTIALS.
// 128x128 tile, BK=64, 4 waves x (4x4) 16x16x32 bf16 MFMA frags.
//  - DOUBLE-BUFFERED K-loop: STAGE(next) issued before COMPUTE(cur), so the
//    barrier's vmcnt drain lands after compute (staging latency hidden).
//  - NO atomics: epilogue writes partial[wi][nt][wc][128][3]. ROUND-4 BUG
//    FIX: wc=0 and wc=1 waves cover DIFFERENT h-column halves and were
//    racing on one slot — each wave now owns its own wc slot; the reduce
//    kernel sums over nt AND wc (32 partials).
// LDS chunk XOR-swizzle kept (pre-swizzled global src + swizzled ds_read).
// ---------------------------------------------------------------------------
#define STAGE(AS, BS, kt)                                         \
  do {                                                            \
    _Pragma("unroll") for (int i_ = 0; i_ < 4; ++i_) {            \
      glds16(aptr[i_] + (kt), (char*)(AS) + (i_ * 256 + t) * 16); \
      glds16(bptr[i_] + (kt), (char*)(BS) + (i_ * 256 + t) * 16); \
    }                                                             \
  } while (0)

#define COMPUTE(AS, BS)                                               \
  do {                                                                \
    _Pragma("unroll") for (int kk_ = 0; kk_ < 2; ++kk_) {             \
      int ch_ = ((kk_ * 4 + g) ^ sx) * 8;                             \
      short8 af_[4], bf_[4];                                          \
      _Pragma("unroll") for (int m_ = 0; m_ < 4; ++m_)                \
          af_[m_] = *(const short8*)&(AS)[arow + m_ * 1024 + ch_];    \
      _Pragma("unroll") for (int n_ = 0; n_ < 4; ++n_)                \
          bf_[n_] = *(const short8*)&(BS)[brow + n_ * 1024 + ch_];    \
      _Pragma("unroll") for (int m_ = 0; m_ < 4; ++m_)                \
          _Pragma("unroll") for (int n_ = 0; n_ < 4; ++n_)            \
              acc[m_][n_] = __builtin_amdgcn_mfma_f32_16x16x32_bf16(  \
                  af_[m_], bf_[n_], acc[m_][n_], 0, 0, 0);            \
    }                                                                 \
  } while (0)

__global__ __launch_bounds__(256) void moe_gemm_kernel(
    const unsigned short* __restrict__ xb, const unsigned short* __restrict__ w1t,
    const float* __restrict__ b1, const float* __restrict__ W2,
    const int* __restrict__ perm, const int* __restrict__ counts,
    const int* __restrict__ offsets, const int* __restrict__ worklist,
    const int* __restrict__ n_wl, float* __restrict__ partial) {
  int nt = blockIdx.x & 15;  // B panel; XCD = bid%8 = nt%8 -> B L2-local
  int wi = blockIdx.x >> 4;
  if (wi >= *n_wl) return;
  int item = worklist[wi];
  int e = item >> 16;
  int mt = item & 0xffff;
  int cnt = counts[e];
  int off = offsets[e];
  int t = threadIdx.x;
  int lane = t & 63;
  int w = t >> 6, wr = w >> 1, wc = w & 1;

  __shared__ int ridx[128];
  __shared__ unsigned short As0[128 * 64];  // slot(r,c) holds chunk c^(r&7)
  __shared__ unsigned short Bs0[128 * 64];
  __shared__ unsigned short As1[128 * 64];
  __shared__ unsigned short Bs1[128 * 64];

  if (t < 128) {
    int m = mt * 128 + t;
    ridx[t] = perm[off + (m < cnt ? m : cnt - 1)];
  }
  __syncthreads();

  // staging addresses: 16B chunk c of row r sourced from global chunk c^(r&7)
  const unsigned short* aptr[4];
  const unsigned short* bptr[4];
#pragma unroll
  for (int i = 0; i < 4; ++i) {
    int idx = i * 256 + t;
    int r = idx >> 3;
    int c = idx & 7;
    int cs = c ^ (r & 7);
    aptr[i] = xb + (size_t)ridx[r] * ND + cs * 8;
    bptr[i] = w1t + ((size_t)(e * NH + nt * 128 + r)) * ND + cs * 8;
  }

  // hoist epilogue weights above K-loop
  int cg = lane & 15;
  int g = lane >> 4;
  float b1v[4];
  float w2v[4][3];
#pragma unroll
  for (int n = 0; n < 4; ++n) {
    int col = nt * 128 + wc * 64 + n * 16 + cg;
    b1v[n] = b1[e * NH + col];
    const float* w2p = W2 + ((size_t)e * NH + col) * NC;
    w2v[n][0] = w2p[0];
    w2v[n][1] = w2p[1];
    w2v[n][2] = w2p[2];
  }

  f32x4 acc[4][4];
#pragma unroll
  for (int m = 0; m < 4; ++m)
#pragma unroll
    for (int n = 0; n < 4; ++n) acc[m][n] = (f32x4){0.f, 0.f, 0.f, 0.f};

  int arow = (wr * 64 + (lane & 15)) * 64;
  int brow = (wc * 64 + (lane & 15)) * 64;
  int sx = lane & 7;

  // double-buffered K-loop: 16 tiles of BK=64
  STAGE(As0, Bs0, 0);
  __syncthreads();
#pragma unroll 1
  for (int it = 0; it < 7; ++it) {
    int kb = it * 128;
    STAGE(As1, Bs1, kb + 64);
    COMPUTE(As0, Bs0);
    __syncthreads();
    STAGE(As0, Bs0, kb + 128);
    COMPUTE(As1, Bs1);
    __syncthreads();
  }
  STAGE(As1, Bs1, 960);
  COMPUTE(As0, Bs0);  // tile kt=896
  __syncthreads();
  COMPUTE(As1, Bs1);  // tile kt=960

  // Epilogue: h = relu(acc + b1); partial[wi][nt][wc][row][c] = sum over this
  // wave's 64 h-cols of h*W2[h][c].
  // C/D frag mapping: col = lane&15, row = (lane>>4)*4 + i   [m89/m91]
  float* pbase = partial + (((size_t)(wi * 16 + nt)) * 2 + wc) * 128 * NC;
#pragma unroll
  for (int m = 0; m < 4; ++m) {
#pragma unroll
    for (int i = 0; i < 4; ++i) {
      float s0 = 0.f, s1 = 0.f, s2 = 0.f;
#pragma unroll
      for (int n = 0; n < 4; ++n) {
        float h = acc[m][n][i] + b1v[n];
        h = h > 0.f ? h : 0.f;
        s0 = fmaf(h, w2v[n][0], s0);
        s1 = fmaf(h, w2v[n][1], s1);
        s2 = fmaf(h, w2v[n][2], s2);
      }
#pragma unroll
      for (int d = 1; d < 16; d <<= 1) {
        s0 += __shfl_xor(s0, d);
        s1 += __shfl_xor(s1, d);
        s2 += __shfl_xor(s2, d);
      }
      if (cg == 0) {
        int rloc = wr * 64 + m * 16 + g * 4 + i;
        float* pp = pbase + rloc * NC;
        pp[0] = s0;
        pp[1] = s1;
        pp[2] = s2;
      }
    }
  }
}

// ---------------------------------------------------------------------------
// Kernel 5: reduce partials over (nt, wc) and write out = b2[e] + sum.
// One block per worklist tile; 384 threads = (row,c) pairs; sum 32 slots.
// Reads stride-384 (coalesced across threads).
// ---------------------------------------------------------------------------
__global__ __launch_bounds__(384) void reduce_kernel(
    const float* __restrict__ partial, const float* __restrict__ b2,
    const int* __restrict__ perm, const int* __restrict__ counts,
    const int* __restrict__ offsets, const int* __restrict__ worklist,
    const int* __restrict__ n_wl, float* __restrict__ out) {
  int wi = blockIdx.x;
  if (wi >= *n_wl) return;
  int item = worklist[wi];
  int e = item >> 16;
  int mt = item & 0xffff;
  int cnt = counts[e];
  int off = offsets[e];
  int j = threadIdx.x;  // row*3 + c
  int r = j / 3, c = j - r * 3;
  int m = mt * 128 + r;
  if (m >= cnt) return;
  const float* p = partial + (size_t)wi * 32 * 384 + j;
  float s = 0.f;
#pragma unroll
  for (int q = 0; q < 32; ++q) s += p[q * 384];
  int tok = perm[off + m];
  out[tok * NC + c] = b2[e * NC + c] + s;
}

// ---------------------------------------------------------------------------
// Workspace layout (~74 MB):
//   [0,   32MiB)       xb  bf16 [16384][1024]
//   [32,  64MiB)       W1T bf16 [8][2048][1024]
//   [64MiB, +132KB)    topics[16384], perm[16384], counts[8], offsets[8],
//                      worklist[256], n_wl
//   [64MiB+132KB, ...) partial f32 [136*16][2][128][3]  (6.68 MB)
// (gemm A-tail duplicate rows produce partials for rloc>=cnt; reduce guards.)
// ---------------------------------------------------------------------------
extern "C" void kernel_launch(void* const* d_in, const int* in_sizes, int n_in,
                              void* d_out, int out_size, void* d_ws,
                              size_t ws_size, hipStream_t stream) {
  const float* x = (const float*)d_in[0];
  const float* Wr = (const float*)d_in[1];
  const float* br = (const float*)d_in[2];
  const float* W1 = (const float*)d_in[3];
  const float* b1 = (const float*)d_in[4];
  const float* W2 = (const float*)d_in[5];
  const float* b2 = (const float*)d_in[6];
  float* out = (float*)d_out;

  char* ws = (char*)d_ws;
  unsigned short* xb = (unsigned short*)ws;
  unsigned short* w1t = (unsigned short*)(ws + (size_t)33554432);
  int* topics = (int*)(ws + (size_t)67108864);
  int* perm = topics + NB;
  int* counts = perm + NB;
  int* offsets = counts + NE;
  int* worklist = offsets + NE;
  int* n_wl = worklist + 256;
  float* partial = (float*)(ws + (size_t)67108864 + 135168);

  router_kernel<<<NB / 4, 256, 0, stream>>>(x, Wr, br, xb, topics);
  ranker_kernel<<<1, 1024, 0, stream>>>(topics, perm, counts, offsets,
                                        worklist, n_wl);
  w1t_kernel<<<NE * 16 * 32, 256, 0, stream>>>(W1, w1t);
  moe_gemm_kernel<<<MAXWL * 16, 256, 0, stream>>>(xb, w1t, b1, W2, perm,
                                                  counts, offsets, worklist,
                                                  n_wl, partial);
  reduce_kernel<<<MAXWL, 384, 0, stream>>>(partial, b2, perm, counts, offsets,
                                           worklist, n_wl, out);
}